// Round 1
// baseline (284.458 us; speedup 1.0000x reference)
//
#include <hip/hip_runtime.h>
#include <hip/hip_bf16.h>

#define B_ 2048
#define N_ 8
#define D_ 1024
#define V_ 4096
#define LN_EPS_ 1e-5f

#define BM 128
#define BN 128
#define BK 32

typedef __bf16 bf16x8 __attribute__((ext_vector_type(8)));
typedef float f32x4 __attribute__((ext_vector_type(4)));

#define GLB(p) ((const __attribute__((address_space(1))) void*)(p))
#define LDSP(p) ((__attribute__((address_space(3))) void*)(p))

// float -> bf16 bits, round-to-nearest-even (inputs are finite)
static __device__ __forceinline__ unsigned short f2bf(float x) {
    union { float f; unsigned int u; } v;
    v.f = x;
    unsigned int r = v.u + 0x7fffu + ((v.u >> 16) & 1u);
    return (unsigned short)(r >> 16);
}

// ---------------------------------------------------------------------------
// Kernel 1: W_pred (N, D, V) f32  ->  Wt (N, V, D) bf16   (transposed, B^T layout)
// ---------------------------------------------------------------------------
__global__ __launch_bounds__(256) void wconv(const float* __restrict__ W,
                                             unsigned short* __restrict__ Wt) {
    __shared__ unsigned short tile[64][65];
    const int n  = blockIdx.z;
    const int v0 = blockIdx.x * 64;
    const int d0 = blockIdx.y * 64;
    const int tx = threadIdx.x;  // 0..15
    const int ty = threadIdx.y;  // 0..15
#pragma unroll
    for (int i = 0; i < 4; ++i) {
        const int d = ty + i * 16;
        const float4 w4 = *(const float4*)&W[((size_t)n * D_ + d0 + d) * V_ + v0 + tx * 4];
        tile[d][tx * 4 + 0] = f2bf(w4.x);
        tile[d][tx * 4 + 1] = f2bf(w4.y);
        tile[d][tx * 4 + 2] = f2bf(w4.z);
        tile[d][tx * 4 + 3] = f2bf(w4.w);
    }
    __syncthreads();
#pragma unroll
    for (int i = 0; i < 4; ++i) {
        const int v = ty + i * 16;
        ushort4 pk;
        pk.x = tile[tx * 4 + 0][v];
        pk.y = tile[tx * 4 + 1][v];
        pk.z = tile[tx * 4 + 2][v];
        pk.w = tile[tx * 4 + 3][v];
        *reinterpret_cast<ushort4*>(&Wt[((size_t)n * V_ + v0 + v) * D_ + d0 + tx * 4]) = pk;
    }
}

// ---------------------------------------------------------------------------
// Kernel 2: gather + cumsum + LayerNorm + exact GELU -> H (N, B, D) bf16
// One block per b. 256 threads, 4 d-elements each.
// ---------------------------------------------------------------------------
__global__ __launch_bounds__(256) void stage1(const float* __restrict__ ie,    // (B, D)
                                              const int* __restrict__ feats,   // (B, N)
                                              const float* __restrict__ emb,   // (N, V, D)
                                              const float* __restrict__ gamma,
                                              const float* __restrict__ beta,
                                              unsigned short* __restrict__ H) { // (N, B, D)
    const int b = blockIdx.x;
    const int t = threadIdx.x;
    const int d0 = t * 4;
    const int lane = t & 63, wid = t >> 6;

    float4 s  = *(const float4*)&ie[(size_t)b * D_ + d0];
    const float4 g4 = *(const float4*)&gamma[d0];
    const float4 be4 = *(const float4*)&beta[d0];

    int fc[N_];
#pragma unroll
    for (int n = 0; n < N_; ++n) fc[n] = feats[b * N_ + n];

    __shared__ float redS[4], redQ[4];

#pragma unroll
    for (int n = 0; n < N_; ++n) {
        float ls = s.x + s.y + s.z + s.w;
        float lq = s.x * s.x + s.y * s.y + s.z * s.z + s.w * s.w;
#pragma unroll
        for (int off = 32; off > 0; off >>= 1) {
            ls += __shfl_down(ls, off, 64);
            lq += __shfl_down(lq, off, 64);
        }
        if (lane == 0) { redS[wid] = ls; redQ[wid] = lq; }
        __syncthreads();
        const float tot  = redS[0] + redS[1] + redS[2] + redS[3];
        const float totq = redQ[0] + redQ[1] + redQ[2] + redQ[3];
        __syncthreads();

        const float mu   = tot * (1.0f / D_);
        const float var  = totq * (1.0f / D_) - mu * mu;
        const float rstd = rsqrtf(var + LN_EPS_);

        float h0 = (s.x - mu) * rstd * g4.x + be4.x;
        float h1 = (s.y - mu) * rstd * g4.y + be4.y;
        float h2 = (s.z - mu) * rstd * g4.z + be4.z;
        float h3 = (s.w - mu) * rstd * g4.w + be4.w;
        h0 = 0.5f * h0 * (1.0f + erff(h0 * 0.70710678f));
        h1 = 0.5f * h1 * (1.0f + erff(h1 * 0.70710678f));
        h2 = 0.5f * h2 * (1.0f + erff(h2 * 0.70710678f));
        h3 = 0.5f * h3 * (1.0f + erff(h3 * 0.70710678f));

        ushort4 pk;
        pk.x = f2bf(h0); pk.y = f2bf(h1); pk.z = f2bf(h2); pk.w = f2bf(h3);
        *reinterpret_cast<ushort4*>(&H[((size_t)n * B_ + b) * D_ + d0]) = pk;

        // advance running sum with feature-n embedding
        const float4 e = *(const float4*)&emb[((size_t)n * V_ + fc[n]) * (size_t)D_ + d0];
        s.x += e.x; s.y += e.y; s.z += e.z; s.w += e.w;
    }
}

// ---------------------------------------------------------------------------
// Kernel 3: logits[b,n,v] = sum_d H[n,b,d] * Wt[n,v,d] + b_pred[n,v]
// m97 structure: 128x128 tile, BK=32, 4 waves, mfma 16x16x32 bf16,
// global_load_lds width-16 staging, 2 barriers per K-step.
// ---------------------------------------------------------------------------
__global__ __launch_bounds__(256) void gemm(const unsigned short* __restrict__ H,   // (N, B, D)
                                            const unsigned short* __restrict__ Wt,  // (N, V, D)
                                            const float* __restrict__ bp,           // (N, V)
                                            float* __restrict__ out) {              // (B, N, V)
    const int vt = blockIdx.x;  // 0..31
    const int mt = blockIdx.y;  // 0..15
    const int n  = blockIdx.z;  // 0..7
    const int t = threadIdx.x;
    const int wid = t >> 6, lane = t & 63;
    const int wr = wid >> 1, wc = wid & 1;

    __shared__ unsigned short shA[BM * BK];  // [128][32] bf16, 8 KB
    __shared__ unsigned short shB[BN * BK];  // [128][32] bf16, 8 KB
    char* ldsA = (char*)shA;
    char* ldsB = (char*)shB;

    const unsigned short* Abase = H  + ((size_t)n * B_ + (size_t)mt * BM) * D_;
    const unsigned short* Bbase = Wt + ((size_t)n * V_ + (size_t)vt * BN) * D_;

    const int row0 = t >> 2;   // 0..63 (issue adds +64)
    const int ks   = t & 3;    // which 8-element k-group

    f32x4 acc[4][4] = {};

    for (int kt = 0; kt < D_; kt += BK) {
        __builtin_amdgcn_global_load_lds(GLB(Abase + (size_t)row0 * D_ + kt + ks * 8),
                                         LDSP(ldsA + t * 16), 16, 0, 0);
        __builtin_amdgcn_global_load_lds(GLB(Abase + (size_t)(row0 + 64) * D_ + kt + ks * 8),
                                         LDSP(ldsA + 4096 + t * 16), 16, 0, 0);
        __builtin_amdgcn_global_load_lds(GLB(Bbase + (size_t)row0 * D_ + kt + ks * 8),
                                         LDSP(ldsB + t * 16), 16, 0, 0);
        __builtin_amdgcn_global_load_lds(GLB(Bbase + (size_t)(row0 + 64) * D_ + kt + ks * 8),
                                         LDSP(ldsB + 4096 + t * 16), 16, 0, 0);
        __syncthreads();

        const int lrow = lane & 15;
        const int lk   = (lane >> 4) * 16;  // byte offset: 8 bf16 per k-group
        bf16x8 af[4], bf[4];
#pragma unroll
        for (int i = 0; i < 4; ++i)
            af[i] = *reinterpret_cast<const bf16x8*>(ldsA + (wr * 64 + i * 16 + lrow) * 64 + lk);
#pragma unroll
        for (int i = 0; i < 4; ++i)
            bf[i] = *reinterpret_cast<const bf16x8*>(ldsB + (wc * 64 + i * 16 + lrow) * 64 + lk);
#pragma unroll
        for (int i = 0; i < 4; ++i)
#pragma unroll
            for (int j = 0; j < 4; ++j)
                acc[i][j] = __builtin_amdgcn_mfma_f32_16x16x32_bf16(af[i], bf[j], acc[i][j], 0, 0, 0);
        __syncthreads();
    }

    // epilogue: C/D layout col = lane&15, row = (lane>>4)*4 + reg
    const int col  = lane & 15;
    const int rgrp = (lane >> 4) * 4;
    float bias[4];
#pragma unroll
    for (int j = 0; j < 4; ++j)
        bias[j] = bp[(size_t)n * V_ + vt * BN + wc * 64 + j * 16 + col];
#pragma unroll
    for (int i = 0; i < 4; ++i) {
        const int grow = mt * BM + wr * 64 + i * 16 + rgrp;
#pragma unroll
        for (int j = 0; j < 4; ++j) {
            const int gcol = vt * BN + wc * 64 + j * 16 + col;
#pragma unroll
            for (int r = 0; r < 4; ++r) {
                out[((size_t)(grow + r) * N_ + n) * V_ + gcol] = acc[i][j][r] + bias[j];
            }
        }
    }
}

// ---------------------------------------------------------------------------
extern "C" void kernel_launch(void* const* d_in, const int* in_sizes, int n_in,
                              void* d_out, int out_size, void* d_ws, size_t ws_size,
                              hipStream_t stream) {
    const float* ie  = (const float*)d_in[0];   // input_embedding (B, D)
    const int*   fts = (const int*)d_in[1];     // features (B, N)
    const float* emb = (const float*)d_in[2];   // embed_tables (N, V, D)
    const float* W   = (const float*)d_in[3];   // W_pred (N, D, V)
    const float* bp  = (const float*)d_in[4];   // b_pred (N, V)
    const float* gam = (const float*)d_in[5];   // ln_gamma (D,)
    const float* bet = (const float*)d_in[6];   // ln_beta (D,)
    float* out = (float*)d_out;

    unsigned short* Wt = (unsigned short*)d_ws;                                   // 64 MiB
    unsigned short* H  = (unsigned short*)((char*)d_ws + (size_t)N_ * V_ * D_ * 2); // +32 MiB

    wconv<<<dim3(V_ / 64, D_ / 64, N_), dim3(16, 16), 0, stream>>>(W, Wt);
    stage1<<<dim3(B_), dim3(256), 0, stream>>>(ie, fts, emb, gam, bet, H);
    gemm<<<dim3(V_ / BN, B_ / BM, N_), dim3(256), 0, stream>>>(H, Wt, bp, out);
}

// Round 2
// 253.974 us; speedup vs baseline: 1.1200x; 1.1200x over previous
//
#include <hip/hip_runtime.h>
#include <hip/hip_bf16.h>

#define B_ 2048
#define N_ 8
#define D_ 1024
#define V_ 4096
#define LN_EPS_ 1e-5f

typedef __bf16 bf16x8 __attribute__((ext_vector_type(8)));
typedef float f32x4 __attribute__((ext_vector_type(4)));

#define GLB(p) ((const __attribute__((address_space(1))) void*)(p))
#define LDSP(p) ((__attribute__((address_space(3))) void*)(p))

static __device__ __forceinline__ unsigned short f2bf(float x) {
    union { float f; unsigned int u; } v;
    v.f = x;
    unsigned int r = v.u + 0x7fffu + ((v.u >> 16) & 1u);
    return (unsigned short)(r >> 16);
}

// ---------------------------------------------------------------------------
// Kernel 1: W_pred (N, D, V) f32 -> Wt (N, V, D) bf16
// ---------------------------------------------------------------------------
__global__ __launch_bounds__(256) void wconv(const float* __restrict__ W,
                                             unsigned short* __restrict__ Wt) {
    __shared__ unsigned short tile[64][65];
    const int n  = blockIdx.z;
    const int v0 = blockIdx.x * 64;
    const int d0 = blockIdx.y * 64;
    const int tx = threadIdx.x;
    const int ty = threadIdx.y;
#pragma unroll
    for (int i = 0; i < 4; ++i) {
        const int d = ty + i * 16;
        const float4 w4 = *(const float4*)&W[((size_t)n * D_ + d0 + d) * V_ + v0 + tx * 4];
        tile[d][tx * 4 + 0] = f2bf(w4.x);
        tile[d][tx * 4 + 1] = f2bf(w4.y);
        tile[d][tx * 4 + 2] = f2bf(w4.z);
        tile[d][tx * 4 + 3] = f2bf(w4.w);
    }
    __syncthreads();
#pragma unroll
    for (int i = 0; i < 4; ++i) {
        const int v = ty + i * 16;
        ushort4 pk;
        pk.x = tile[tx * 4 + 0][v];
        pk.y = tile[tx * 4 + 1][v];
        pk.z = tile[tx * 4 + 2][v];
        pk.w = tile[tx * 4 + 3][v];
        *reinterpret_cast<ushort4*>(&Wt[((size_t)n * V_ + v0 + v) * D_ + d0 + tx * 4]) = pk;
    }
}

// ---------------------------------------------------------------------------
// Kernel 2: gather + cumsum + LN + exact GELU -> H (N, B, D) bf16
// ---------------------------------------------------------------------------
__global__ __launch_bounds__(256) void stage1(const float* __restrict__ ie,
                                              const int* __restrict__ feats,
                                              const float* __restrict__ emb,
                                              const float* __restrict__ gamma,
                                              const float* __restrict__ beta,
                                              unsigned short* __restrict__ H) {
    const int b = blockIdx.x;
    const int t = threadIdx.x;
    const int d0 = t * 4;
    const int lane = t & 63, wid = t >> 6;

    float4 s  = *(const float4*)&ie[(size_t)b * D_ + d0];
    const float4 g4 = *(const float4*)&gamma[d0];
    const float4 be4 = *(const float4*)&beta[d0];

    int fc[N_];
#pragma unroll
    for (int n = 0; n < N_; ++n) fc[n] = feats[b * N_ + n];

    __shared__ float redS[4], redQ[4];

#pragma unroll
    for (int n = 0; n < N_; ++n) {
        float ls = s.x + s.y + s.z + s.w;
        float lq = s.x * s.x + s.y * s.y + s.z * s.z + s.w * s.w;
#pragma unroll
        for (int off = 32; off > 0; off >>= 1) {
            ls += __shfl_down(ls, off, 64);
            lq += __shfl_down(lq, off, 64);
        }
        if (lane == 0) { redS[wid] = ls; redQ[wid] = lq; }
        __syncthreads();
        const float tot  = redS[0] + redS[1] + redS[2] + redS[3];
        const float totq = redQ[0] + redQ[1] + redQ[2] + redQ[3];
        __syncthreads();

        const float mu   = tot * (1.0f / D_);
        const float var  = totq * (1.0f / D_) - mu * mu;
        const float rstd = rsqrtf(var + LN_EPS_);

        float h0 = (s.x - mu) * rstd * g4.x + be4.x;
        float h1 = (s.y - mu) * rstd * g4.y + be4.y;
        float h2 = (s.z - mu) * rstd * g4.z + be4.z;
        float h3 = (s.w - mu) * rstd * g4.w + be4.w;
        h0 = 0.5f * h0 * (1.0f + erff(h0 * 0.70710678f));
        h1 = 0.5f * h1 * (1.0f + erff(h1 * 0.70710678f));
        h2 = 0.5f * h2 * (1.0f + erff(h2 * 0.70710678f));
        h3 = 0.5f * h3 * (1.0f + erff(h3 * 0.70710678f));

        ushort4 pk;
        pk.x = f2bf(h0); pk.y = f2bf(h1); pk.z = f2bf(h2); pk.w = f2bf(h3);
        *reinterpret_cast<ushort4*>(&H[((size_t)n * B_ + b) * D_ + d0]) = pk;

        const float4 e = *(const float4*)&emb[((size_t)n * V_ + fc[n]) * (size_t)D_ + d0];
        s.x += e.x; s.y += e.y; s.z += e.z; s.w += e.w;
    }
}

// ---------------------------------------------------------------------------
// Kernel 3: 256x256x(BK=64) 8-wave, 4-phase/K-tile pipelined GEMM.
//   logits[b,n,v] = sum_d H[n,b,d] * Wt[n,v,d] + b_pred[n,v]
// LDS: 2 buffers x (A 32KB + B 32KB) = 128 KB dynamic.
// Each K-tile: 8 gload_lds (B0 B1 | B2 B3 | A0 A1 | A2 A3), units = 64 rows.
// Wave (wr,wc): rows i*32+wr*16 (i=0..7), cols wc*64+j*16 (j=0..3).
// Phase p computes i in {2p,2p+1} over full K=64 -> A-quadrant p = stage unit p.
// Swizzle: physical 16B slot = logical ^ (row&7); inverse applied on global src.
// ---------------------------------------------------------------------------
#define MF(a, b, c) __builtin_amdgcn_mfma_f32_16x16x32_bf16((a), (b), (c), 0, 0, 0)

#define STG_A(u, kt, bb) __builtin_amdgcn_global_load_lds( \
    GLB(Ab + (size_t)((u) * 64 + srow) * D_ + (kt) + gsl), \
    LDSP(lds + (bb) + (u) * 8192 + t * 16), 16, 0, 0)
#define STG_B(u, kt, bb) __builtin_amdgcn_global_load_lds( \
    GLB(Bb + (size_t)((u) * 64 + srow) * D_ + (kt) + gsl), \
    LDSP(lds + (bb) + 32768 + (u) * 8192 + t * 16), 16, 0, 0)

#define RD_A(i, ks, bb) (*(const bf16x8*)(lds + (bb) + ((i) >> 1) * 8192 + \
    (((i) & 1) * 32 + wr * 16 + lrow) * 128 + ((((ks) * 4 + lkq) ^ sw) * 16)))
#define RD_B(j, ks, bb) (*(const bf16x8*)(lds + (bb) + 32768 + wc * 8192 + \
    ((j) * 16 + lrow) * 128 + ((((ks) * 4 + lkq) ^ sw) * 16)))

#define QUADP(i0, i1) \
    _Pragma("unroll") for (int j = 0; j < 4; ++j) { \
        acc[i0][j] = MF(A00, Bf[j][0], acc[i0][j]); \
        acc[i0][j] = MF(A01, Bf[j][1], acc[i0][j]); \
        acc[i1][j] = MF(A10, Bf[j][0], acc[i1][j]); \
        acc[i1][j] = MF(A11, Bf[j][1], acc[i1][j]); \
    }

#define TILE(KT, bc, bn) { \
    bf16x8 Bf[4][2]; \
    asm volatile("s_waitcnt vmcnt(3)" ::: "memory"); \
    __builtin_amdgcn_s_barrier(); \
    _Pragma("unroll") for (int j = 0; j < 4; ++j) { Bf[j][0] = RD_B(j, 0, bc); Bf[j][1] = RD_B(j, 1, bc); } \
    { bf16x8 A00 = RD_A(0, 0, bc), A01 = RD_A(0, 1, bc), A10 = RD_A(1, 0, bc), A11 = RD_A(1, 1, bc); \
      STG_B(0, (KT) + 64, bn); STG_B(1, (KT) + 64, bn); \
      __builtin_amdgcn_s_setprio(1); QUADP(0, 1); __builtin_amdgcn_s_setprio(0); } \
    asm volatile("s_waitcnt vmcnt(4)" ::: "memory"); \
    __builtin_amdgcn_s_barrier(); \
    { bf16x8 A00 = RD_A(2, 0, bc), A01 = RD_A(2, 1, bc), A10 = RD_A(3, 0, bc), A11 = RD_A(3, 1, bc); \
      STG_B(2, (KT) + 64, bn); STG_B(3, (KT) + 64, bn); \
      __builtin_amdgcn_s_setprio(1); QUADP(2, 3); __builtin_amdgcn_s_setprio(0); } \
    asm volatile("s_waitcnt vmcnt(4)" ::: "memory"); \
    __builtin_amdgcn_s_barrier(); \
    { bf16x8 A00 = RD_A(4, 0, bc), A01 = RD_A(4, 1, bc), A10 = RD_A(5, 0, bc), A11 = RD_A(5, 1, bc); \
      STG_A(0, (KT) + 64, bn); STG_A(1, (KT) + 64, bn); \
      __builtin_amdgcn_s_setprio(1); QUADP(4, 5); __builtin_amdgcn_s_setprio(0); } \
    asm volatile("s_waitcnt vmcnt(6)" ::: "memory"); \
    __builtin_amdgcn_s_barrier(); \
    { bf16x8 A00 = RD_A(6, 0, bc), A01 = RD_A(6, 1, bc), A10 = RD_A(7, 0, bc), A11 = RD_A(7, 1, bc); \
      STG_A(2, (KT) + 64, bn); STG_A(3, (KT) + 64, bn); \
      __builtin_amdgcn_s_setprio(1); QUADP(6, 7); __builtin_amdgcn_s_setprio(0); } \
}

#define TILE_LAST(bc) { \
    bf16x8 Bf[4][2]; \
    asm volatile("s_waitcnt vmcnt(3)" ::: "memory"); \
    __builtin_amdgcn_s_barrier(); \
    _Pragma("unroll") for (int j = 0; j < 4; ++j) { Bf[j][0] = RD_B(j, 0, bc); Bf[j][1] = RD_B(j, 1, bc); } \
    { bf16x8 A00 = RD_A(0, 0, bc), A01 = RD_A(0, 1, bc), A10 = RD_A(1, 0, bc), A11 = RD_A(1, 1, bc); \
      __builtin_amdgcn_s_setprio(1); QUADP(0, 1); __builtin_amdgcn_s_setprio(0); } \
    asm volatile("s_waitcnt vmcnt(2)" ::: "memory"); \
    __builtin_amdgcn_s_barrier(); \
    { bf16x8 A00 = RD_A(2, 0, bc), A01 = RD_A(2, 1, bc), A10 = RD_A(3, 0, bc), A11 = RD_A(3, 1, bc); \
      __builtin_amdgcn_s_setprio(1); QUADP(2, 3); __builtin_amdgcn_s_setprio(0); } \
    asm volatile("s_waitcnt vmcnt(1)" ::: "memory"); \
    __builtin_amdgcn_s_barrier(); \
    { bf16x8 A00 = RD_A(4, 0, bc), A01 = RD_A(4, 1, bc), A10 = RD_A(5, 0, bc), A11 = RD_A(5, 1, bc); \
      __builtin_amdgcn_s_setprio(1); QUADP(4, 5); __builtin_amdgcn_s_setprio(0); } \
    asm volatile("s_waitcnt vmcnt(0)" ::: "memory"); \
    __builtin_amdgcn_s_barrier(); \
    { bf16x8 A00 = RD_A(6, 0, bc), A01 = RD_A(6, 1, bc), A10 = RD_A(7, 0, bc), A11 = RD_A(7, 1, bc); \
      __builtin_amdgcn_s_setprio(1); QUADP(6, 7); __builtin_amdgcn_s_setprio(0); } \
}

__global__ __launch_bounds__(512, 2) void gemm8(const unsigned short* __restrict__ H,
                                                const unsigned short* __restrict__ Wt,
                                                const float* __restrict__ bp,
                                                float* __restrict__ out) {
    extern __shared__ char lds[];
    const int vt = blockIdx.x, mt = blockIdx.y, n = blockIdx.z;
    const int t = threadIdx.x;
    const int wid = t >> 6, lane = t & 63;
    const int wr = wid >> 2, wc = wid & 3;

    const unsigned short* Ab = H  + ((size_t)n * B_ + (size_t)mt * 256) * D_;
    const unsigned short* Bb = Wt + ((size_t)n * V_ + (size_t)vt * 256) * D_;

    const int srow = t >> 3;                       // staging row within 64-row unit
    const int gsl  = ((t & 7) ^ (srow & 7)) * 8;   // inverse-swizzled source slot (elements)

    const int lrow = lane & 15;
    const int lkq  = lane >> 4;
    const int sw   = lane & 7;

    f32x4 acc[8][4] = {};

    // prologue: stage tile 0 into buf0 (order: B0 B1 B2 B3 A0 A1 A2 A3)
    STG_B(0, 0, 0); STG_B(1, 0, 0); STG_B(2, 0, 0); STG_B(3, 0, 0);
    STG_A(0, 0, 0); STG_A(1, 0, 0); STG_A(2, 0, 0); STG_A(3, 0, 0);

    int kt = 0;
#pragma unroll 1
    for (int it = 0; it < 7; ++it) {       // tiles 0..13
        TILE(kt, 0, 65536); kt += 64;
        TILE(kt, 65536, 0); kt += 64;
    }
    TILE(kt, 0, 65536);                    // tile 14 (stages tile 15)
    TILE_LAST(65536);                      // tile 15

    // epilogue
    const int col = lane & 15;
    const int rg  = (lane >> 4) * 4;
    const int gc0 = vt * 256 + wc * 64 + col;
    float bias[4];
#pragma unroll
    for (int j = 0; j < 4; ++j) bias[j] = bp[(size_t)n * V_ + gc0 + j * 16];
#pragma unroll
    for (int i = 0; i < 8; ++i) {
        const int row = mt * 256 + i * 32 + wr * 16 + rg;
#pragma unroll
        for (int j = 0; j < 4; ++j) {
            const int gcol = gc0 + j * 16;
#pragma unroll
            for (int r = 0; r < 4; ++r) {
                out[((size_t)(row + r) * N_ + n) * V_ + gcol] = acc[i][j][r] + bias[j];
            }
        }
    }
}

// ---------------------------------------------------------------------------
extern "C" void kernel_launch(void* const* d_in, const int* in_sizes, int n_in,
                              void* d_out, int out_size, void* d_ws, size_t ws_size,
                              hipStream_t stream) {
    const float* ie  = (const float*)d_in[0];
    const int*   fts = (const int*)d_in[1];
    const float* emb = (const float*)d_in[2];
    const float* W   = (const float*)d_in[3];
    const float* bp  = (const float*)d_in[4];
    const float* gam = (const float*)d_in[5];
    const float* bet = (const float*)d_in[6];
    float* out = (float*)d_out;

    unsigned short* Wt = (unsigned short*)d_ws;                                     // 64 MiB
    unsigned short* H  = (unsigned short*)((char*)d_ws + (size_t)N_ * V_ * D_ * 2); // +32 MiB

    (void)hipFuncSetAttribute(reinterpret_cast<const void*>(gemm8),
                              hipFuncAttributeMaxDynamicSharedMemorySize, 131072);

    wconv<<<dim3(V_ / 64, D_ / 64, N_), dim3(16, 16), 0, stream>>>(W, Wt);
    stage1<<<dim3(B_), dim3(256), 0, stream>>>(ie, fts, emb, gam, bet, H);
    gemm8<<<dim3(V_ / 256, B_ / 256, N_), 512, 131072, stream>>>(H, Wt, bp, out);
}